// Round 15
// baseline (528.620 us; speedup 1.0000x reference)
//
#include <hip/hip_runtime.h>
#include <cmath>

// Problem constants
constexpr int B_  = 2;
constexpr int T_  = 512;
constexpr int DM_ = 1024;
constexpr int H_  = 16;
constexpr int DH_ = 64;
constexpr int D_  = 32;
constexpr int R_  = 4;
constexpr int BH_ = B_ * H_;   // 32
constexpr int PROW = 40;
constexpr int NBLK = 512;

typedef __bf16 bf16x8 __attribute__((ext_vector_type(8)));
typedef float  f32x4  __attribute__((ext_vector_type(4)));
typedef unsigned short u16x8 __attribute__((ext_vector_type(8)));

__device__ __forceinline__ unsigned short f2bf(float f) {
    unsigned u = __float_as_uint(f);
    return (unsigned short)((u + 0x7fffu + ((u >> 16) & 1u)) >> 16);  // RNE
}
__device__ __forceinline__ float bf2f(unsigned short v) {
    return __uint_as_float((unsigned)v << 16);
}
__device__ __forceinline__ void gload16(const void* g, void* l) {
    __builtin_amdgcn_global_load_lds(
        (const __attribute__((address_space(1))) void*)g,
        (__attribute__((address_space(3))) void*)l, 16, 0, 0);
}

// Hand-rolled grid barrier (sense-reversing, device-scope atomics).
// Release: __threadfence() (agent fence -> L2 writeback).  Acquire: agent-
// scope atomic load spin (bypasses stale per-XCD caches).  Timeout: if
// blocks are not co-resident the spin breaks after ~50M cycles -> wrong
// results (bench fails cleanly) instead of a hang.
__device__ __forceinline__ void gsync(int* cnt, int* gen) {
    __syncthreads();
    if (threadIdx.x == 0) {
        __threadfence();
        int g = __hip_atomic_load(gen, __ATOMIC_RELAXED, __HIP_MEMORY_SCOPE_AGENT);
        int old = __hip_atomic_fetch_add(cnt, 1, __ATOMIC_ACQ_REL,
                                         __HIP_MEMORY_SCOPE_AGENT);
        if (old == NBLK - 1) {
            __hip_atomic_store(cnt, 0, __ATOMIC_RELAXED, __HIP_MEMORY_SCOPE_AGENT);
            __hip_atomic_fetch_add(gen, 1, __ATOMIC_RELEASE,
                                   __HIP_MEMORY_SCOPE_AGENT);
        } else {
            long long t0 = clock64();
            while (__hip_atomic_load(gen, __ATOMIC_ACQUIRE,
                                     __HIP_MEMORY_SCOPE_AGENT) == g) {
                if (clock64() - t0 > 50000000LL) break;   // ~20 ms escape
            }
        }
    }
    __syncthreads();
}

// -------------------------------------------------------------------------
// Persistent kernel: prep -> qkv gemm -> feat -> attn -> out, separated by
// 4 grid barriers.  512 blocks x 256 thr; LDS union 43.5 KB -> 3/CU cap,
// 2/CU resident; launch_bounds(256,2) caps VGPR at 256.
// -------------------------------------------------------------------------
__global__ __launch_bounds__(256, 2) void mega_kernel(
    const float* __restrict__ x, const float* __restrict__ Wq,
    const float* __restrict__ Wk, const float* __restrict__ Wv,
    const float* __restrict__ Wo, const float* __restrict__ Wqm,
    const float* __restrict__ Wkm, const float* __restrict__ Wmetric,
    const float* __restrict__ temp_p, float* __restrict__ out,
    unsigned char* wsb, int* bar)
{
    // ---- workspace layout (matches host) ----
    float* q_raw = (float*)wsb;
    float* k_raw = q_raw + (size_t)BH_ * T_ * DH_;
    float* q2p   = k_raw + (size_t)BH_ * T_ * DH_;
    float* k2    = q2p   + (size_t)BH_ * T_;
    unsigned short* xb   = (unsigned short*)(k2 + (size_t)BH_ * T_);
    unsigned short* wqb  = xb   + (size_t)DM_ * DM_;
    unsigned short* wkb  = wqb  + (size_t)DM_ * DM_;
    unsigned short* wvb  = wkb  + (size_t)DM_ * DM_;
    unsigned short* wob  = wvb  + (size_t)DM_ * DM_;
    unsigned short* a_hi = wob  + (size_t)DM_ * DM_;
    unsigned short* a_lo = a_hi + (size_t)BH_ * T_ * D_;
    unsigned short* kmhi = a_lo + (size_t)BH_ * T_ * D_;
    unsigned short* kmlo = kmhi + (size_t)BH_ * T_ * D_;
    unsigned short* Urb  = kmlo + (size_t)BH_ * T_ * D_;
    unsigned short* vT   = Urb  + (size_t)BH_ * R_ * T_ * D_;
    unsigned short* ctxb = vT   + (size_t)BH_ * DH_ * T_;
    int* bcnt = bar;
    int* bgen = bar + 1;

    __shared__ union {
        struct { unsigned short Ls[64][72]; } prep;                       // 9.2 KB
        struct { __align__(16) unsigned short As[64 * 64];
                 __align__(16) unsigned short Bs[64 * 64]; } g;           // 16 KB
        struct { float qrs[4][64]; float qms[4][32];
                 float Us[4][128]; float Uqs[4][4]; } f;                  // 3.7 KB
        struct { __align__(16) unsigned short P[4][32 * PROW];
                 __align__(16) float OP[4][32][64]; float ML[4][32]; } a; // 43.5 KB
    } sh;

    const int vb   = blockIdx.x;        // 0..511
    const int tid  = threadIdx.x;
    const int lane = tid & 63;
    const int w    = tid >> 6;
    const int l15  = lane & 15, quad = lane >> 4;

    // ================= S0: prep (1280 units) =================
    for (int u = vb; u < 1280; u += NBLK) {
        const int z = u >> 8, idx = u & 255;
        if (z == 4) {
            int base = idx * 4096 + tid * 16;
#pragma unroll
            for (int c = 0; c < 4; ++c) {
                float4 v = *(const float4*)&x[base + c * 4];
                ushort4 o = { f2bf(v.x), f2bf(v.y), f2bf(v.z), f2bf(v.w) };
                *(ushort4*)&xb[base + c * 4] = o;
            }
        } else {
            const float* W = (z == 0) ? Wq : (z == 1) ? Wk : (z == 2) ? Wv : Wo;
            unsigned short* O = (z == 0) ? wqb : (z == 1) ? wkb
                              : (z == 2) ? wvb : wob;
            const int k0 = (idx & 15) * 64;
            const int n0 = (idx >> 4) * 64;
            __syncthreads();               // LDS reuse across u-iterations
#pragma unroll
            for (int it = 0; it < 4; ++it) {
                int r = it * 16 + (tid >> 4);
                int c = (tid & 15) * 4;
                float4 v4 = *(const float4*)&W[(size_t)(k0 + r) * DM_ + n0 + c];
                sh.prep.Ls[c + 0][r] = f2bf(v4.x); sh.prep.Ls[c + 1][r] = f2bf(v4.y);
                sh.prep.Ls[c + 2][r] = f2bf(v4.z); sh.prep.Ls[c + 3][r] = f2bf(v4.w);
            }
            __syncthreads();
#pragma unroll
            for (int it = 0; it < 2; ++it) {
                int nl = it * 32 + (tid >> 3);
                int kc = (tid & 7) * 8;
                *(u16x8*)&O[(size_t)(n0 + nl) * DM_ + k0 + kc] =
                    *(const u16x8*)&sh.prep.Ls[nl][kc];
            }
        }
    }
    gsync(bcnt, bgen);

    // ================= S1: qkv gemm, BK=64 swizzled (768 units) ============
    for (int u = vb; u < 768; u += NBLK) {
        const int bm = (u / 48) * 64;
        const int n0 = (u % 48) * 64;
        const int which = n0 >> 10;
        const int bn = n0 & 1023;
        const unsigned short* Bt = (which == 0) ? wqb : (which == 1) ? wkb : wvb;

        const int srow = tid >> 3, kcs = tid & 7, kcg = kcs ^ (srow & 7);
        const unsigned short* Ap0 = xb + (size_t)(bm + srow) * DM_ + kcg * 8;
        const unsigned short* Bp0 = Bt + (size_t)(bn + srow) * DM_ + kcg * 8;
        const unsigned short* Ap1 = Ap0 + 32 * DM_;
        const unsigned short* Bp1 = Bp0 + 32 * DM_;
        unsigned short* As0 = &sh.g.As[tid * 8];
        unsigned short* Bs0 = &sh.g.Bs[tid * 8];
        unsigned short* As1 = As0 + 2048;     // chunk tid+256 (ELEMENTS)
        unsigned short* Bs1 = Bs0 + 2048;
        const int wm = (w & 1) * 32, wn = (w >> 1) * 32;

        f32x4 acc[2][2] = {};
        __syncthreads();                      // LDS reuse across u-iterations
        for (int k0 = 0; k0 < DM_; k0 += 64) {
            gload16(Ap0 + k0, As0);
            gload16(Ap1 + k0, As1);
            gload16(Bp0 + k0, Bs0);
            gload16(Bp1 + k0, Bs1);
            __syncthreads();
            bf16x8 af[2][2], bfr[2][2];
#pragma unroll
            for (int ki = 0; ki < 2; ++ki)
#pragma unroll
                for (int i = 0; i < 2; ++i) {
                    int ra = wm + i * 16 + l15;
                    int rb = wn + i * 16 + l15;
                    int kch = ki * 4 + quad;
                    af[ki][i]  = *(const bf16x8*)&sh.g.As[ra * 64 + (kch ^ (ra & 7)) * 8];
                    bfr[ki][i] = *(const bf16x8*)&sh.g.Bs[rb * 64 + (kch ^ (rb & 7)) * 8];
                }
#pragma unroll
            for (int mi = 0; mi < 2; ++mi)
#pragma unroll
                for (int ni = 0; ni < 2; ++ni) {
                    acc[mi][ni] = __builtin_amdgcn_mfma_f32_16x16x32_bf16(
                        af[0][mi], bfr[0][ni], acc[mi][ni], 0, 0, 0);
                    acc[mi][ni] = __builtin_amdgcn_mfma_f32_16x16x32_bf16(
                        af[1][mi], bfr[1][ni], acc[mi][ni], 0, 0, 0);
                }
            __syncthreads();
        }
        const int h = bn >> 6;
#pragma unroll
        for (int mi = 0; mi < 2; ++mi)
#pragma unroll
            for (int ni = 0; ni < 2; ++ni) {
                f32x4 a = acc[mi][ni];
                int d = wn + ni * 16 + l15;
#pragma unroll
                for (int r = 0; r < 4; ++r) {
                    int row = bm + wm + mi * 16 + quad * 4 + r;
                    int bb = row >> 9, tt = row & (T_ - 1);
                    if (which == 2) {
                        vT[(((size_t)bb * H_ + h) * DH_ + d) * T_ + tt] = f2bf(a[r]);
                    } else {
                        float* C = (which == 0) ? q_raw : k_raw;
                        C[(((size_t)bb * H_ + h) * T_ + tt) * DH_ + d] = a[r];
                    }
                }
            }
    }
    gsync(bcnt, bgen);

    // ================= S2: features (8192 units, 4 rows each) ==============
    for (int u = vb; u < 8192; u += NBLK) {
        const int side = u & 1;                    // 0=q 1=k (block-uniform)
        const int row  = (u >> 1) * 4 + w;         // bh*T + t
        const int t    = row & (T_ - 1);
        const int bh   = row >> 9;
        const float* raw = side ? k_raw : q_raw;
        const float* Wm  = side ? Wkm   : Wqm;

        float rv = raw[(size_t)row * 64 + lane];
        int   fi = lane & 31;
        float ang = (float)t * expf((float)fi * -0.28782313662425575f);
        float s, c;
        sincosf(ang, &s, &c);
        float partner = __shfl_xor(rv, 32);
        float qr = (lane < 32) ? (rv * c - partner * s) : (partner * s + rv * c);
        sh.f.qrs[w][lane] = qr;                    // per-wave scratch
        __syncthreads();

        if (lane < 32) {
            float acc = 0.f;
#pragma unroll 8
            for (int d = 0; d < 64; ++d) acc += sh.f.qrs[w][d] * Wm[d * 32 + lane];
            sh.f.qms[w][lane] = 1.0f / (1.0f + __expf(-acc));
        }
        __syncthreads();

        if (side == 0) {
            float a0 = 0.f, a1 = 0.f;
#pragma unroll 8
            for (int m = 0; m < 32; ++m) {
                float qv = sh.f.qms[w][m];
                a0 += qv * Wmetric[m * 128 + lane];
                a1 += qv * Wmetric[m * 128 + 64 + lane];
            }
            sh.f.Us[w][lane] = a0; sh.f.Us[w][64 + lane] = a1;
            {
                int r0 = lane & 3, d0 = lane >> 2;
                int d1 = 16 + (lane >> 2);
                Urb[(((size_t)bh * R_ + r0) * T_ + t) * D_ + d0] = f2bf(a0);
                Urb[(((size_t)bh * R_ + r0) * T_ + t) * D_ + d1] = f2bf(a1);
            }
            __syncthreads();
            if (lane < 4) {
                float acc = 0.f;
#pragma unroll
                for (int d = 0; d < 32; ++d)
                    acc += sh.f.Us[w][d * 4 + lane] * sh.f.qms[w][d];
                sh.f.Uqs[w][lane] = acc;
            }
            __syncthreads();
            if (lane < 32) {
                float b = sh.f.Uqs[w][0] * sh.f.Us[w][lane * 4 + 0]
                        + sh.f.Uqs[w][1] * sh.f.Us[w][lane * 4 + 1]
                        + sh.f.Uqs[w][2] * sh.f.Us[w][lane * 4 + 2]
                        + sh.f.Uqs[w][3] * sh.f.Us[w][lane * 4 + 3];
                float a = sh.f.qms[w][lane] + b;
                unsigned short hi = f2bf(a);
                unsigned short lo = f2bf(a - bf2f(hi));
                size_t off = (size_t)row * 32 + lane;
                a_hi[off] = hi; a_lo[off] = lo;
            }
            if (lane == 0) {
                float acc = 0.f;
#pragma unroll
                for (int m = 0; m < 32; ++m)
                    acc += sh.f.qms[w][m] * sh.f.qms[w][m];
#pragma unroll
                for (int r = 0; r < 4; ++r)
                    acc += sh.f.Uqs[w][r] * sh.f.Uqs[w][r];
                q2p[row] = acc;
            }
            __syncthreads();
        } else {
            if (lane < 32) {
                float v = sh.f.qms[w][lane];
                unsigned short hi = f2bf(v);
                unsigned short lo = f2bf(v - bf2f(hi));
                size_t off = (size_t)row * 32 + lane;
                kmhi[off] = hi; kmlo[off] = lo;
            }
            if (lane == 0) {
                float acc = 0.f;
#pragma unroll
                for (int m = 0; m < 32; ++m)
                    acc += sh.f.qms[w][m] * sh.f.qms[w][m];
                k2[row] = acc;
            }
            __syncthreads();
        }
    }
    gsync(bcnt, bgen);

    // ================= S3: attention (512 units, 1 per block) ==============
    {
        const int itile = vb >> 5, bh = vb & 31;
        const int i0 = itile * 32;
        const float inv_temp = 1.0f / fmaxf(temp_p[0], 0.5f);

        bf16x8 Ahi[2], Alo[2], Aur[4][2];
#pragma unroll
        for (int mi = 0; mi < 2; ++mi) {
            size_t ab = ((size_t)bh * T_ + i0 + mi * 16 + l15) * 32 + quad * 8;
            Ahi[mi] = *(const bf16x8*)&a_hi[ab];
            Alo[mi] = *(const bf16x8*)&a_lo[ab];
#pragma unroll
            for (int r = 0; r < 4; ++r)
                Aur[r][mi] = *(const bf16x8*)
                    &Urb[(((size_t)bh * R_ + r) * T_ + i0 + mi * 16 + l15) * 32 + quad * 8];
        }
        float q2r[2][4];
#pragma unroll
        for (int mi = 0; mi < 2; ++mi)
#pragma unroll
            for (int rg = 0; rg < 4; ++rg)
                q2r[mi][rg] = q2p[(size_t)bh * T_ + i0 + mi * 16 + quad * 4 + rg];

        f32x4 Oacc[2][4] = {};
        float psum[2][4] = {};

        for (int jt = w; jt <= itile; jt += 4) {
            const int j0 = jt * 32;
            bf16x8 Bhi[2], Blo[2];
#pragma unroll
            for (int ni = 0; ni < 2; ++ni) {
                size_t kb = ((size_t)bh * T_ + j0 + ni * 16 + l15) * 32 + quad * 8;
                Bhi[ni] = *(const bf16x8*)&kmhi[kb];
                Blo[ni] = *(const bf16x8*)&kmlo[kb];
            }
            f32x4 acc[2][2] = {};
#pragma unroll
            for (int mi = 0; mi < 2; ++mi)
#pragma unroll
                for (int ni = 0; ni < 2; ++ni) {
                    acc[mi][ni] = __builtin_amdgcn_mfma_f32_16x16x32_bf16(
                        Alo[mi], Bhi[ni], acc[mi][ni], 0, 0, 0);
                    acc[mi][ni] = __builtin_amdgcn_mfma_f32_16x16x32_bf16(
                        Ahi[mi], Blo[ni], acc[mi][ni], 0, 0, 0);
                    acc[mi][ni] = __builtin_amdgcn_mfma_f32_16x16x32_bf16(
                        Ahi[mi], Bhi[ni], acc[mi][ni], 0, 0, 0);
                }
            f32x4 sq[2][2] = {};
#pragma unroll
            for (int r = 0; r < 4; ++r) {
                f32x4 ar[2][2] = {};
#pragma unroll
                for (int mi = 0; mi < 2; ++mi)
#pragma unroll
                    for (int ni = 0; ni < 2; ++ni)
                        ar[mi][ni] = __builtin_amdgcn_mfma_f32_16x16x32_bf16(
                            Aur[r][mi], Bhi[ni], ar[mi][ni], 0, 0, 0);
#pragma unroll
                for (int mi = 0; mi < 2; ++mi)
#pragma unroll
                    for (int ni = 0; ni < 2; ++ni)
                        sq[mi][ni] += ar[mi][ni] * ar[mi][ni];
            }
            float k2c[2];
#pragma unroll
            for (int ni = 0; ni < 2; ++ni)
                k2c[ni] = k2[(size_t)bh * T_ + j0 + ni * 16 + l15];
            const bool diag = (jt == itile);
#pragma unroll
            for (int mi = 0; mi < 2; ++mi)
#pragma unroll
                for (int ni = 0; ni < 2; ++ni)
#pragma unroll
                    for (int rg = 0; rg < 4; ++rg) {
                        float dist = q2r[mi][rg] + k2c[ni]
                                   - 2.f * acc[mi][ni][rg] + sq[mi][ni][rg];
                        float sc = -fmaxf(dist, 0.f) * inv_temp;
                        if (diag && (ni * 16 + l15) > (mi * 16 + quad * 4 + rg))
                            sc = -1e30f;
                        float p = __expf(sc);   // scores <= 0: m=0 softmax exact
                        psum[mi][rg] += p;
                        sh.a.P[w][(mi * 16 + quad * 4 + rg) * PROW + ni * 16 + l15] = f2bf(p);
                    }
            bf16x8 Pf[2], Vf[4];
#pragma unroll
            for (int mi = 0; mi < 2; ++mi)
                Pf[mi] = *(const bf16x8*)&sh.a.P[w][(mi * 16 + l15) * PROW + quad * 8];
#pragma unroll
            for (int n4 = 0; n4 < 4; ++n4)
                Vf[n4] = *(const bf16x8*)
                    &vT[((size_t)bh * DH_ + n4 * 16 + l15) * T_ + j0 + quad * 8];
#pragma unroll
            for (int mi = 0; mi < 2; ++mi)
#pragma unroll
                for (int n4 = 0; n4 < 4; ++n4)
                    Oacc[mi][n4] = __builtin_amdgcn_mfma_f32_16x16x32_bf16(
                        Pf[mi], Vf[n4], Oacc[mi][n4], 0, 0, 0);
        }

#pragma unroll
        for (int mi = 0; mi < 2; ++mi)
#pragma unroll
            for (int rg = 0; rg < 4; ++rg) {
                float v = psum[mi][rg];
                v += __shfl_xor(v, 1); v += __shfl_xor(v, 2);
                v += __shfl_xor(v, 4); v += __shfl_xor(v, 8);
                psum[mi][rg] = v;
            }
        if (l15 == 0)
#pragma unroll
            for (int mi = 0; mi < 2; ++mi)
#pragma unroll
                for (int rg = 0; rg < 4; ++rg)
                    sh.a.ML[w][mi * 16 + quad * 4 + rg] = psum[mi][rg];
#pragma unroll
        for (int mi = 0; mi < 2; ++mi)
#pragma unroll
            for (int n4 = 0; n4 < 4; ++n4)
#pragma unroll
                for (int rg = 0; rg < 4; ++rg)
                    sh.a.OP[w][mi * 16 + quad * 4 + rg][n4 * 16 + l15] = Oacc[mi][n4][rg];
        __syncthreads();

        const int ii = tid >> 3, ds = tid & 7;
        float l = sh.a.ML[0][ii] + sh.a.ML[1][ii] + sh.a.ML[2][ii] + sh.a.ML[3][ii];
        float O[8] = {};
#pragma unroll
        for (int wv = 0; wv < 4; ++wv) {
            float4 o0 = *(const float4*)&sh.a.OP[wv][ii][ds * 8];
            float4 o1 = *(const float4*)&sh.a.OP[wv][ii][ds * 8 + 4];
            O[0] += o0.x; O[1] += o0.y; O[2] += o0.z; O[3] += o0.w;
            O[4] += o1.x; O[5] += o1.y; O[6] += o1.z; O[7] += o1.w;
        }
        const float inv = 1.0f / l;
        const int b = bh >> 4, h = bh & 15;
        u16x8 o;
#pragma unroll
        for (int dd = 0; dd < 8; ++dd) o[dd] = f2bf(O[dd] * inv);
        *(u16x8*)&ctxb[((size_t)b * T_ + i0 + ii) * DM_ + h * 64 + ds * 8] = o;
    }
    gsync(bcnt, bgen);

    // ================= S4: output projection (256 units) ==================
    if (vb < 256) {
        const int bm = (vb >> 4) * 64;
        const int bn = (vb & 15) * 64;
        const int srow = tid >> 3, kcs = tid & 7, kcg = kcs ^ (srow & 7);
        const unsigned short* Ap0 = ctxb + (size_t)(bm + srow) * DM_ + kcg * 8;
        const unsigned short* Bp0 = wob  + (size_t)(bn + srow) * DM_ + kcg * 8;
        const unsigned short* Ap1 = Ap0 + 32 * DM_;
        const unsigned short* Bp1 = Bp0 + 32 * DM_;
        unsigned short* As0 = &sh.g.As[tid * 8];
        unsigned short* Bs0 = &sh.g.Bs[tid * 8];
        unsigned short* As1 = As0 + 2048;     // chunk tid+256 (ELEMENTS)
        unsigned short* Bs1 = Bs0 + 2048;
        const int wm = (w & 1) * 32, wn = (w >> 1) * 32;

        f32x4 acc[2][2] = {};
        for (int k0 = 0; k0 < DM_; k0 += 64) {
            gload16(Ap0 + k0, As0);
            gload16(Ap1 + k0, As1);
            gload16(Bp0 + k0, Bs0);
            gload16(Bp1 + k0, Bs1);
            __syncthreads();
            bf16x8 af[2][2], bfr[2][2];
#pragma unroll
            for (int ki = 0; ki < 2; ++ki)
#pragma unroll
                for (int i = 0; i < 2; ++i) {
                    int ra = wm + i * 16 + l15;
                    int rb = wn + i * 16 + l15;
                    int kch = ki * 4 + quad;
                    af[ki][i]  = *(const bf16x8*)&sh.g.As[ra * 64 + (kch ^ (ra & 7)) * 8];
                    bfr[ki][i] = *(const bf16x8*)&sh.g.Bs[rb * 64 + (kch ^ (rb & 7)) * 8];
                }
#pragma unroll
            for (int mi = 0; mi < 2; ++mi)
#pragma unroll
                for (int ni = 0; ni < 2; ++ni) {
                    acc[mi][ni] = __builtin_amdgcn_mfma_f32_16x16x32_bf16(
                        af[0][mi], bfr[0][ni], acc[mi][ni], 0, 0, 0);
                    acc[mi][ni] = __builtin_amdgcn_mfma_f32_16x16x32_bf16(
                        af[1][mi], bfr[1][ni], acc[mi][ni], 0, 0, 0);
                }
            __syncthreads();
        }
#pragma unroll
        for (int mi = 0; mi < 2; ++mi)
#pragma unroll
            for (int ni = 0; ni < 2; ++ni) {
                f32x4 a = acc[mi][ni];
                int col = bn + wn + ni * 16 + l15;
#pragma unroll
                for (int r = 0; r < 4; ++r) {
                    int row = bm + wm + mi * 16 + quad * 4 + r;
                    out[(size_t)row * DM_ + col] = a[r];
                }
            }
    }
}

// -------------------------------------------------------------------------
extern "C" void kernel_launch(void* const* d_in, const int* in_sizes, int n_in,
                              void* d_out, int out_size, void* d_ws, size_t ws_size,
                              hipStream_t stream)
{
    const float* x       = (const float*)d_in[0];
    const float* Wq      = (const float*)d_in[1];
    const float* Wk      = (const float*)d_in[2];
    const float* Wv      = (const float*)d_in[3];
    const float* Wo      = (const float*)d_in[4];
    const float* Wqm     = (const float*)d_in[5];
    const float* Wkm     = (const float*)d_in[6];
    const float* Wmetric = (const float*)d_in[7];
    const float* temp    = (const float*)d_in[8];
    float* out = (float*)d_out;
    unsigned char* wsb = (unsigned char*)d_ws;

    // mirror the device-side layout to find the barrier slot
    float* q_raw = (float*)wsb;
    float* k_raw = q_raw + (size_t)BH_ * T_ * DH_;
    float* q2p   = k_raw + (size_t)BH_ * T_ * DH_;
    float* k2    = q2p   + (size_t)BH_ * T_;
    unsigned short* xb   = (unsigned short*)(k2 + (size_t)BH_ * T_);
    unsigned short* ctxb = xb
        + 5 * (size_t)DM_ * DM_            // wqb..wob + a_hi start
        + 4 * (size_t)BH_ * T_ * D_        // a_hi,a_lo,kmhi,kmlo
        + (size_t)BH_ * R_ * T_ * D_       // Urb
        + (size_t)BH_ * DH_ * T_;          // vT
    int* bar = (int*)(ctxb + (size_t)BH_ * DH_ * T_);

    hipMemsetAsync(bar, 0, 2 * sizeof(int), stream);
    mega_kernel<<<dim3(NBLK), dim3(256), 0, stream>>>(
        x, Wq, Wk, Wv, Wo, Wqm, Wkm, Wmetric, temp, out, wsb, bar);
}

// Round 16
// 146.846 us; speedup vs baseline: 3.5998x; 3.5998x over previous
//
#include <hip/hip_runtime.h>
#include <cmath>

// Problem constants
constexpr int B_  = 2;
constexpr int T_  = 512;
constexpr int DM_ = 1024;
constexpr int H_  = 16;
constexpr int DH_ = 64;
constexpr int D_  = 32;
constexpr int R_  = 4;
constexpr int BH_ = B_ * H_;   // 32

typedef __bf16 bf16x8 __attribute__((ext_vector_type(8)));
typedef float  f32x4  __attribute__((ext_vector_type(4)));
typedef unsigned short u16x8 __attribute__((ext_vector_type(8)));

__device__ __forceinline__ unsigned short f2bf(float f) {
    unsigned u = __float_as_uint(f);
    return (unsigned short)((u + 0x7fffu + ((u >> 16) & 1u)) >> 16);  // RNE
}
__device__ __forceinline__ float bf2f(unsigned short v) {
    return __uint_as_float((unsigned)v << 16);
}
__device__ __forceinline__ void gload16(const void* g, void* l) {
    __builtin_amdgcn_global_load_lds(
        (const __attribute__((address_space(1))) void*)g,
        (__attribute__((address_space(3))) void*)l, 16, 0, 0);
}

// -------------------------------------------------------------------------
// Prep: z=0..3 -> transpose+convert Wq/Wk/Wv/Wo to (N x K) bf16;
//       z=4    -> convert x to bf16 row-major.  (unchanged from R11)
// -------------------------------------------------------------------------
__global__ __launch_bounds__(256) void prep_kernel(
    const float* __restrict__ x,
    const float* __restrict__ Wq, const float* __restrict__ Wk,
    const float* __restrict__ Wv, const float* __restrict__ Wo,
    unsigned short* __restrict__ xb,
    unsigned short* __restrict__ wqb, unsigned short* __restrict__ wkb,
    unsigned short* __restrict__ wvb, unsigned short* __restrict__ wob)
{
    const int t = threadIdx.x;
    const int z = blockIdx.z;
    if (z == 4) {
        int base = (blockIdx.y * 16 + blockIdx.x) * 4096 + t * 16;
#pragma unroll
        for (int c = 0; c < 4; ++c) {
            float4 v = *(const float4*)&x[base + c * 4];
            ushort4 o = { f2bf(v.x), f2bf(v.y), f2bf(v.z), f2bf(v.w) };
            *(ushort4*)&xb[base + c * 4] = o;
        }
        return;
    }
    __shared__ __align__(16) unsigned short Ls[64][72];
    const float* W = (z == 0) ? Wq : (z == 1) ? Wk : (z == 2) ? Wv : Wo;
    unsigned short* O = (z == 0) ? wqb : (z == 1) ? wkb : (z == 2) ? wvb : wob;
    const int k0 = blockIdx.x * 64;
    const int n0 = blockIdx.y * 64;
#pragma unroll
    for (int it = 0; it < 4; ++it) {
        int r = it * 16 + (t >> 4);
        int c = (t & 15) * 4;
        float4 v4 = *(const float4*)&W[(size_t)(k0 + r) * DM_ + n0 + c];
        Ls[c + 0][r] = f2bf(v4.x); Ls[c + 1][r] = f2bf(v4.y);
        Ls[c + 2][r] = f2bf(v4.z); Ls[c + 3][r] = f2bf(v4.w);
    }
    __syncthreads();
#pragma unroll
    for (int it = 0; it < 2; ++it) {
        int nl = it * 32 + (t >> 3);
        int kc = (t & 7) * 8;
        *(u16x8*)&O[(size_t)(n0 + nl) * DM_ + k0 + kc] = *(const u16x8*)&Ls[nl][kc];
    }
}

// -------------------------------------------------------------------------
// 64x64-tile bf16 MFMA GEMM, BK=64 swizzled, DOUBLE-BUFFERED LDS.
// m139-style raw s_barrier + manual s_waitcnt vmcnt(4): the 4 prefetch
// loads for tile k+1 stay in flight across the barrier; we only drain the
// 4 loads of tile k (8 outstanding -> wait to 4 = oldest 4 complete).
// Hazards: barrier1 separates iter-(k-1) reads of buf_next from iter-k
// writes; vmcnt+barrier2 orders cur-tile writes before cur-tile reads.
// Low-occupancy regime (grid-capped 3 blocks/CU) where R14 measured
// MfmaUtil=3.7% -> staging latency exposed; dbuf hides it.
// EPI==0: q/k -> fp32 head layout, v -> bf16 vT[bh][dh][t].  EPI==1: plain C.
// -------------------------------------------------------------------------
template <int EPI>
__global__ __launch_bounds__(256) void mfma_gemm_db(
    const unsigned short* __restrict__ A,
    const unsigned short* __restrict__ Bt0,
    const unsigned short* __restrict__ Bt1,
    const unsigned short* __restrict__ Bt2,
    float* __restrict__ C0, float* __restrict__ C1,
    unsigned short* __restrict__ vT)
{
    __shared__ __align__(16) unsigned short As[2][64 * 64];   // 16 KB x2
    __shared__ __align__(16) unsigned short Bs[2][64 * 64];   // total 32 KB
    const int tid  = threadIdx.x;
    const int lane = tid & 63;
    const int w    = tid >> 6;
    const int wm   = (w & 1) * 32;
    const int wn   = (w >> 1) * 32;
    const int l15  = lane & 15, quad = lane >> 4;

    const int bm = blockIdx.y * 64;
    int bn, which = 0;
    const unsigned short* Bt;
    if (EPI == 0) {
        int n0 = blockIdx.x * 64;
        which = n0 >> 10;
        bn = n0 & 1023;
        Bt = (which == 0) ? Bt0 : (which == 1) ? Bt1 : Bt2;
    } else {
        bn = blockIdx.x * 64;
        Bt = Bt0;
    }

    const int srow = tid >> 3, kcs = tid & 7, kcg = kcs ^ (srow & 7);
    const unsigned short* Ap0 = A  + (size_t)(bm + srow) * DM_ + kcg * 8;
    const unsigned short* Bp0 = Bt + (size_t)(bn + srow) * DM_ + kcg * 8;
    const unsigned short* Ap1 = Ap0 + 32 * DM_;
    const unsigned short* Bp1 = Bp0 + 32 * DM_;

    // prologue: tile 0 into buffer 0
    gload16(Ap0, &As[0][tid * 8]);
    gload16(Ap1, &As[0][tid * 8 + 2048]);
    gload16(Bp0, &Bs[0][tid * 8]);
    gload16(Bp1, &Bs[0][tid * 8 + 2048]);

    f32x4 acc[2][2] = {};
#pragma unroll
    for (int k = 0; k < 16; ++k) {
        const int cur = k & 1, nxt = cur ^ 1;
        // barrier1: all waves done reading buf[nxt] (iter k-1's frags)
        __builtin_amdgcn_s_barrier();
        if (k + 1 < 16) {
            const int off = (k + 1) * 64;
            gload16(Ap0 + off, &As[nxt][tid * 8]);
            gload16(Ap1 + off, &As[nxt][tid * 8 + 2048]);
            gload16(Bp0 + off, &Bs[nxt][tid * 8]);
            gload16(Bp1 + off, &Bs[nxt][tid * 8 + 2048]);
            __builtin_amdgcn_s_waitcnt(0x0F74);   // vmcnt(4): cur tile done
        } else {
            __builtin_amdgcn_s_waitcnt(0x0F70);   // vmcnt(0): last tile
        }
        // barrier2: everyone's cur-tile loads complete & visible
        __builtin_amdgcn_s_barrier();

        bf16x8 af[2][2], bfr[2][2];
#pragma unroll
        for (int ki = 0; ki < 2; ++ki)
#pragma unroll
            for (int i = 0; i < 2; ++i) {
                int ra = wm + i * 16 + l15;
                int rb = wn + i * 16 + l15;
                int kch = ki * 4 + quad;
                af[ki][i]  = *(const bf16x8*)&As[cur][ra * 64 + (kch ^ (ra & 7)) * 8];
                bfr[ki][i] = *(const bf16x8*)&Bs[cur][rb * 64 + (kch ^ (rb & 7)) * 8];
            }
#pragma unroll
        for (int mi = 0; mi < 2; ++mi)
#pragma unroll
            for (int ni = 0; ni < 2; ++ni) {
                acc[mi][ni] = __builtin_amdgcn_mfma_f32_16x16x32_bf16(
                    af[0][mi], bfr[0][ni], acc[mi][ni], 0, 0, 0);
                acc[mi][ni] = __builtin_amdgcn_mfma_f32_16x16x32_bf16(
                    af[1][mi], bfr[1][ni], acc[mi][ni], 0, 0, 0);
            }
    }

#pragma unroll
    for (int mi = 0; mi < 2; ++mi)
#pragma unroll
        for (int ni = 0; ni < 2; ++ni) {
            f32x4 a = acc[mi][ni];
            int col = wn + ni * 16 + l15;
#pragma unroll
            for (int r = 0; r < 4; ++r) {
                int row = bm + wm + mi * 16 + quad * 4 + r;
                if (EPI == 0) {
                    int h = bn >> 6, d = col;       // 64-wide tile == one head
                    int bb = row >> 9, tt = row & (T_ - 1);
                    if (which == 2) {
                        vT[(((size_t)bb * H_ + h) * DH_ + d) * T_ + tt] = f2bf(a[r]);
                    } else {
                        float* C = (which == 0) ? C0 : C1;
                        C[(((size_t)bb * H_ + h) * T_ + tt) * DH_ + d] = a[r];
                    }
                } else {
                    C0[(size_t)row * DM_ + bn + col] = a[r];
                }
            }
        }
}

// -------------------------------------------------------------------------
// Per-row features (unchanged from R11 — the proven high-parallelism form).
// -------------------------------------------------------------------------
__global__ __launch_bounds__(256) void feat_both(
    const float* __restrict__ q_raw, const float* __restrict__ k_raw,
    const float* __restrict__ Wqm,   const float* __restrict__ Wkm,
    const float* __restrict__ Wmetric,
    unsigned short* __restrict__ a_hi, unsigned short* __restrict__ a_lo,
    unsigned short* __restrict__ km_hi, unsigned short* __restrict__ km_lo,
    float* __restrict__ q2p, float* __restrict__ k2,
    unsigned short* __restrict__ Urb)
{
    const bool QSIDE = (blockIdx.y == 0);
    const float* raw = QSIDE ? q_raw : k_raw;
    const float* Wm  = QSIDE ? Wqm   : Wkm;

    __shared__ float qrs[4][64];
    __shared__ float qms[4][32];
    __shared__ float Us[4][128];
    __shared__ float Uqs[4][4];
    const int tid  = threadIdx.x;
    const int w    = tid >> 6;
    const int lane = tid & 63;
    const int row  = blockIdx.x * 4 + w;       // bh*T + t
    const int t    = row & (T_ - 1);
    const int bh   = row >> 9;

    float rv = raw[(size_t)row * 64 + lane];
    int   fi = lane & 31;
    float ang = (float)t * expf((float)fi * -0.28782313662425575f);
    float s, c;
    sincosf(ang, &s, &c);
    float partner = __shfl_xor(rv, 32);
    float qr = (lane < 32) ? (rv * c - partner * s) : (partner * s + rv * c);
    qrs[w][lane] = qr;
    __syncthreads();

    if (lane < 32) {
        float acc = 0.f;
#pragma unroll 8
        for (int d = 0; d < 64; ++d) acc += qrs[w][d] * Wm[d * 32 + lane];
        qms[w][lane] = 1.0f / (1.0f + __expf(-acc));
    }
    __syncthreads();

    if (QSIDE) {
        float a0 = 0.f, a1 = 0.f;
#pragma unroll 8
        for (int m = 0; m < 32; ++m) {
            float qv = qms[w][m];
            a0 += qv * Wmetric[m * 128 + lane];
            a1 += qv * Wmetric[m * 128 + 64 + lane];
        }
        Us[w][lane] = a0; Us[w][64 + lane] = a1;
        {
            int r0 = lane & 3, d0 = lane >> 2;
            int d1 = 16 + (lane >> 2);
            Urb[(((size_t)bh * R_ + r0) * T_ + t) * D_ + d0] = f2bf(a0);
            Urb[(((size_t)bh * R_ + r0) * T_ + t) * D_ + d1] = f2bf(a1);
        }
        __syncthreads();
        if (lane < 4) {
            float acc = 0.f;
#pragma unroll
            for (int d = 0; d < 32; ++d) acc += Us[w][d * 4 + lane] * qms[w][d];
            Uqs[w][lane] = acc;
        }
        __syncthreads();
        if (lane < 32) {
            float b = Uqs[w][0] * Us[w][lane * 4 + 0]
                    + Uqs[w][1] * Us[w][lane * 4 + 1]
                    + Uqs[w][2] * Us[w][lane * 4 + 2]
                    + Uqs[w][3] * Us[w][lane * 4 + 3];
            float a = qms[w][lane] + b;
            unsigned short hi = f2bf(a);
            unsigned short lo = f2bf(a - bf2f(hi));
            size_t off = (size_t)row * 32 + lane;
            a_hi[off] = hi; a_lo[off] = lo;
        }
        if (lane == 0) {
            float acc = 0.f;
#pragma unroll
            for (int m = 0; m < 32; ++m) acc += qms[w][m] * qms[w][m];
#pragma unroll
            for (int r = 0; r < 4; ++r) acc += Uqs[w][r] * Uqs[w][r];
            q2p[row] = acc;
        }
    } else {
        if (lane < 32) {
            float v = qms[w][lane];
            unsigned short hi = f2bf(v);
            unsigned short lo = f2bf(v - bf2f(hi));
            size_t off = (size_t)row * 32 + lane;
            km_hi[off] = hi; km_lo[off] = lo;
        }
        if (lane == 0) {
            float acc = 0.f;
#pragma unroll
            for (int m = 0; m < 32; ++m) acc += qms[w][m] * qms[w][m];
            k2[row] = acc;
        }
    }
}

// -------------------------------------------------------------------------
// MFMA attention (unchanged from Round 9/11).
// -------------------------------------------------------------------------
constexpr int PROW = 40;
__global__ __launch_bounds__(256) void attn_mfma(
    const unsigned short* __restrict__ a_hi, const unsigned short* __restrict__ a_lo,
    const unsigned short* __restrict__ km_hi, const unsigned short* __restrict__ km_lo,
    const unsigned short* __restrict__ Urb,
    const float* __restrict__ q2p, const float* __restrict__ k2,
    const float* __restrict__ temp_p, const unsigned short* __restrict__ vT,
    unsigned short* __restrict__ ctxb)
{
    __shared__ __align__(16) unsigned short P_lds[4][32 * PROW];
    __shared__ __align__(16) float OP[4][32][64];
    __shared__ float ML[4][32];

    const int itile = blockIdx.x, bh = blockIdx.y;
    const int i0 = itile * 32;
    const int tid = threadIdx.x, w = tid >> 6, lane = tid & 63;
    const int l15 = lane & 15, quad = lane >> 4;

    const float inv_temp = 1.0f / fmaxf(temp_p[0], 0.5f);

    bf16x8 Ahi[2], Alo[2], Aur[4][2];
#pragma unroll
    for (int mi = 0; mi < 2; ++mi) {
        size_t ab = ((size_t)bh * T_ + i0 + mi * 16 + l15) * 32 + quad * 8;
        Ahi[mi] = *(const bf16x8*)&a_hi[ab];
        Alo[mi] = *(const bf16x8*)&a_lo[ab];
#pragma unroll
        for (int r = 0; r < 4; ++r)
            Aur[r][mi] = *(const bf16x8*)
                &Urb[(((size_t)bh * R_ + r) * T_ + i0 + mi * 16 + l15) * 32 + quad * 8];
    }
    float q2r[2][4];
#pragma unroll
    for (int mi = 0; mi < 2; ++mi)
#pragma unroll
        for (int rg = 0; rg < 4; ++rg)
            q2r[mi][rg] = q2p[(size_t)bh * T_ + i0 + mi * 16 + quad * 4 + rg];

    f32x4 Oacc[2][4] = {};
    float psum[2][4] = {};

    for (int jt = w; jt <= itile; jt += 4) {
        const int j0 = jt * 32;
        bf16x8 Bhi[2], Blo[2];
#pragma unroll
        for (int ni = 0; ni < 2; ++ni) {
            size_t kb = ((size_t)bh * T_ + j0 + ni * 16 + l15) * 32 + quad * 8;
            Bhi[ni] = *(const bf16x8*)&km_hi[kb];
            Blo[ni] = *(const bf16x8*)&km_lo[kb];
        }
        f32x4 acc[2][2] = {};
#pragma unroll
        for (int mi = 0; mi < 2; ++mi)
#pragma unroll
            for (int ni = 0; ni < 2; ++ni) {
                acc[mi][ni] = __builtin_amdgcn_mfma_f32_16x16x32_bf16(
                    Alo[mi], Bhi[ni], acc[mi][ni], 0, 0, 0);
                acc[mi][ni] = __builtin_amdgcn_mfma_f32_16x16x32_bf16(
                    Ahi[mi], Blo[ni], acc[mi][ni], 0, 0, 0);
                acc[mi][ni] = __builtin_amdgcn_mfma_f32_16x16x32_bf16(
                    Ahi[mi], Bhi[ni], acc[mi][ni], 0, 0, 0);
            }
        f32x4 sq[2][2] = {};
#pragma unroll
        for (int r = 0; r < 4; ++r) {
            f32x4 ar[2][2] = {};
#pragma unroll
            for (int mi = 0; mi < 2; ++mi)
#pragma unroll
                for (int ni = 0; ni < 2; ++ni)
                    ar[mi][ni] = __builtin_amdgcn_mfma_f32_16x16x32_bf16(
                        Aur[r][mi], Bhi[ni], ar[mi][ni], 0, 0, 0);
#pragma unroll
            for (int mi = 0; mi < 2; ++mi)
#pragma unroll
                for (int ni = 0; ni < 2; ++ni)
                    sq[mi][ni] += ar[mi][ni] * ar[mi][ni];
        }
        float k2c[2];
#pragma unroll
        for (int ni = 0; ni < 2; ++ni)
            k2c[ni] = k2[(size_t)bh * T_ + j0 + ni * 16 + l15];
        const bool diag = (jt == itile);
#pragma unroll
        for (int mi = 0; mi < 2; ++mi)
#pragma unroll
            for (int ni = 0; ni < 2; ++ni)
#pragma unroll
                for (int rg = 0; rg < 4; ++rg) {
                    float dist = q2r[mi][rg] + k2c[ni]
                               - 2.f * acc[mi][ni][rg] + sq[mi][ni][rg];
                    float sc = -fmaxf(dist, 0.f) * inv_temp;
                    if (diag && (ni * 16 + l15) > (mi * 16 + quad * 4 + rg))
                        sc = -1e30f;
                    float p = __expf(sc);      // scores <= 0: m=0 softmax exact
                    psum[mi][rg] += p;
                    P_lds[w][(mi * 16 + quad * 4 + rg) * PROW + ni * 16 + l15] = f2bf(p);
                }
        bf16x8 Pf[2], Vf[4];
#pragma unroll
        for (int mi = 0; mi < 2; ++mi)
            Pf[mi] = *(const bf16x8*)&P_lds[w][(mi * 16 + l15) * PROW + quad * 8];
#pragma unroll
        for (int n4 = 0; n4 < 4; ++n4)
            Vf[n4] = *(const bf16x8*)
                &vT[((size_t)bh * DH_ + n4 * 16 + l15) * T_ + j0 + quad * 8];
#pragma unroll
        for (int mi = 0; mi < 2; ++mi)
#pragma unroll
            for (int n4 = 0; n4 < 4; ++n4)
                Oacc[mi][n4] = __builtin_amdgcn_mfma_f32_16x16x32_bf16(
                    Pf[mi], Vf[n4], Oacc[mi][n4], 0, 0, 0);
    }

#pragma unroll
    for (int mi = 0; mi < 2; ++mi)
#pragma unroll
        for (int rg = 0; rg < 4; ++rg) {
            float v = psum[mi][rg];
            v += __shfl_xor(v, 1); v += __shfl_xor(v, 2);
            v += __shfl_xor(v, 4); v += __shfl_xor(v, 8);
            psum[mi][rg] = v;
        }
    if (l15 == 0)
#pragma unroll
        for (int mi = 0; mi < 2; ++mi)
#pragma unroll
            for (int rg = 0; rg < 4; ++rg)
                ML[w][mi * 16 + quad * 4 + rg] = psum[mi][rg];
#pragma unroll
    for (int mi = 0; mi < 2; ++mi)
#pragma unroll
        for (int n4 = 0; n4 < 4; ++n4)
#pragma unroll
            for (int rg = 0; rg < 4; ++rg)
                OP[w][mi * 16 + quad * 4 + rg][n4 * 16 + l15] = Oacc[mi][n4][rg];
    __syncthreads();

    const int ii = tid >> 3, ds = tid & 7;
    float l = ML[0][ii] + ML[1][ii] + ML[2][ii] + ML[3][ii];
    float O[8] = {};
#pragma unroll
    for (int wv = 0; wv < 4; ++wv) {
        float4 o0 = *(const float4*)&OP[wv][ii][ds * 8];
        float4 o1 = *(const float4*)&OP[wv][ii][ds * 8 + 4];
        O[0] += o0.x; O[1] += o0.y; O[2] += o0.z; O[3] += o0.w;
        O[4] += o1.x; O[5] += o1.y; O[6] += o1.z; O[7] += o1.w;
    }
    const float inv = 1.0f / l;
    const int b = bh >> 4, h = bh & 15;
    u16x8 o;
#pragma unroll
    for (int dd = 0; dd < 8; ++dd) o[dd] = f2bf(O[dd] * inv);
    *(u16x8*)&ctxb[((size_t)b * T_ + i0 + ii) * DM_ + h * 64 + ds * 8] = o;
}

// -------------------------------------------------------------------------
extern "C" void kernel_launch(void* const* d_in, const int* in_sizes, int n_in,
                              void* d_out, int out_size, void* d_ws, size_t ws_size,
                              hipStream_t stream)
{
    const float* x       = (const float*)d_in[0];
    const float* Wq      = (const float*)d_in[1];
    const float* Wk      = (const float*)d_in[2];
    const float* Wv      = (const float*)d_in[3];
    const float* Wo      = (const float*)d_in[4];
    const float* Wqm     = (const float*)d_in[5];
    const float* Wkm     = (const float*)d_in[6];
    const float* Wmetric = (const float*)d_in[7];
    const float* temp    = (const float*)d_in[8];
    float* out = (float*)d_out;
    float* ws  = (float*)d_ws;

    // fp32 region
    float* q_raw = ws;                                  // 1,048,576 f
    float* k_raw = q_raw + (size_t)BH_ * T_ * DH_;      // 1,048,576 f
    float* q2p   = k_raw + (size_t)BH_ * T_ * DH_;      //    16,384 f
    float* k2    = q2p   + (size_t)BH_ * T_;            //    16,384 f
    // u16 region
    unsigned short* xb   = (unsigned short*)(k2 + (size_t)BH_ * T_);
    unsigned short* wqb  = xb   + (size_t)DM_ * DM_;
    unsigned short* wkb  = wqb  + (size_t)DM_ * DM_;
    unsigned short* wvb  = wkb  + (size_t)DM_ * DM_;
    unsigned short* wob  = wvb  + (size_t)DM_ * DM_;
    unsigned short* a_hi = wob  + (size_t)DM_ * DM_;
    unsigned short* a_lo = a_hi + (size_t)BH_ * T_ * D_;
    unsigned short* kmhi = a_lo + (size_t)BH_ * T_ * D_;
    unsigned short* kmlo = kmhi + (size_t)BH_ * T_ * D_;
    unsigned short* Urb  = kmlo + (size_t)BH_ * T_ * D_;   // BH*R*T*D
    unsigned short* vT   = Urb  + (size_t)BH_ * R_ * T_ * D_;
    unsigned short* ctxb = (unsigned short*)q_raw;  // q_raw dead after feat
    // total ~ 30 MB (<< proven 59 MB)

    prep_kernel<<<dim3(16, 16, 5), 256, 0, stream>>>(
        x, Wq, Wk, Wv, Wo, xb, wqb, wkb, wvb, wob);
    mfma_gemm_db<0><<<dim3(48, 16), 256, 0, stream>>>(
        xb, wqb, wkb, wvb, q_raw, k_raw, vT);
    feat_both<<<dim3(BH_ * T_ / 4, 2), 256, 0, stream>>>(
        q_raw, k_raw, Wqm, Wkm, Wmetric,
        a_hi, a_lo, kmhi, kmlo, q2p, k2, Urb);
    attn_mfma<<<dim3(T_ / 32, BH_), 256, 0, stream>>>(
        a_hi, a_lo, kmhi, kmlo, Urb, q2p, k2, temp, vT, ctxb);
    mfma_gemm_db<1><<<dim3(16, 16), 256, 0, stream>>>(
        ctxb, wob, nullptr, nullptr, out, nullptr, nullptr);
}